// Round 1
// baseline (1505.246 us; speedup 1.0000x reference)
//
#include <hip/hip_runtime.h>
#include <hip/hip_bf16.h>

#define NE      4
#define DIM     2048      // model dim: K of gemm1, N of gemm2
#define FF      2048      // per-expert hidden: N of gemm1, K of gemm2
#define NTOK    16384
#define VOCABSZ 100000
#define TPE     (VOCABSZ / NE)

typedef __attribute__((ext_vector_type(8))) short bf16x8;
typedef __attribute__((ext_vector_type(4))) float f32x4;

#define GPTR(p) ((const __attribute__((address_space(1))) void*)(p))
#define LPTR(p) ((__attribute__((address_space(3))) void*)(p))

__device__ __forceinline__ unsigned short f2bf(float f) {
  unsigned u = __builtin_bit_cast(unsigned, f);
  u += 0x7fffu + ((u >> 16) & 1u);          // RNE
  return (unsigned short)(u >> 16);
}

__device__ __forceinline__ bf16x8 pack8(float4 a, float4 b) {
  bf16x8 r;
  r[0] = (short)f2bf(a.x); r[1] = (short)f2bf(a.y);
  r[2] = (short)f2bf(a.z); r[3] = (short)f2bf(a.w);
  r[4] = (short)f2bf(b.x); r[5] = (short)f2bf(b.y);
  r[6] = (short)f2bf(b.z); r[7] = (short)f2bf(b.w);
  return r;
}

// meta layout: [0..3]=counts  [4..7]=cursors  [8..11]=offsets
__global__ void k_init(int* meta) { if (threadIdx.x < 12) meta[threadIdx.x] = 0; }

__global__ void k_assign(const int* __restrict__ tok, int* __restrict__ eid,
                         int* __restrict__ meta) {
  int i = blockIdx.x * 256 + threadIdx.x;
  int t = tok[i];
  t = t < 0 ? 0 : (t >= VOCABSZ ? VOCABSZ - 1 : t);
  int e = t / TPE; if (e > NE - 1) e = NE - 1;
  eid[i] = e;
  atomicAdd(&meta[e], 1);
}

__global__ void k_prefix(int* meta) {
  if (threadIdx.x == 0 && blockIdx.x == 0) {
    int s = 0;
    for (int e = 0; e < NE; ++e) { meta[8 + e] = s; s += meta[e]; }
  }
}

__global__ void k_scatter(const int* __restrict__ eid, int* __restrict__ meta,
                          int* __restrict__ perm) {
  int i = blockIdx.x * 256 + threadIdx.x;
  int e = eid[i];
  int pos = meta[8 + e] + atomicAdd(&meta[4 + e], 1);
  perm[pos] = i;
}

// cast the three stacked weight tensors fp32 -> bf16 (contiguous in ws)
__global__ void k_cast(const float* __restrict__ s0, const float* __restrict__ s1,
                       const float* __restrict__ s2, unsigned short* __restrict__ dst) {
  const float* s = blockIdx.y == 0 ? s0 : (blockIdx.y == 1 ? s1 : s2);
  unsigned short* d = dst + (size_t)blockIdx.y * ((size_t)NE * FF * DIM);
  size_t i = ((size_t)blockIdx.x * 256 + threadIdx.x) * 8;
  float4 a = *(const float4*)(s + i);
  float4 b = *(const float4*)(s + i + 4);
  *(bf16x8*)(d + i) = pack8(a, b);
}

// ---------------- GEMM1: H = silu(X Wg^T) * (X Wu^T), per-expert grouped rows
__global__ __launch_bounds__(256) void k_gemm1(
    const float* __restrict__ X,
    const unsigned short* __restrict__ Wg,
    const unsigned short* __restrict__ Wu,
    const int* __restrict__ meta,
    const int* __restrict__ perm,
    unsigned short* __restrict__ Hb)
{
  const int NT = FF / 128;      // 16
  const int MT = NTOK / 128;    // 128
  int bx = blockIdx.x;
  int e  = bx / (MT * NT);
  int rr = bx % (MT * NT);
  int mt = rr / NT, nt = rr % NT;
  int cnt = meta[e];
  if (mt * 128 >= cnt) return;
  int base  = meta[8 + e];
  int mrows = cnt - mt * 128; if (mrows > 128) mrows = 128;

  __shared__ unsigned short As[128 * 32];
  __shared__ unsigned short Bg[128 * 32];
  __shared__ unsigned short Bu[128 * 32];

  int t = threadIdx.x;
  int lane = t & 63, wid = t >> 6;
  int wm = wid >> 1, wn = wid & 1;              // 2x2 waves, each 64x64

  // A staging: fp32 gather through perm, 1 row per 2 threads
  int row_a = t >> 1;
  int kseg  = (t & 1) * 16;
  int gl = mt * 128 + row_a; if (gl >= cnt) gl = cnt - 1;   // clamp
  const float* xsrc = X + (size_t)perm[base + gl] * DIM + kseg;

  // B staging: global_load_lds, per-lane global src, wave-uniform LDS dest
  const unsigned short* wg_src = Wg + (size_t)e * FF * DIM
                               + (size_t)(nt * 128 + (t >> 2)) * DIM + (t & 3) * 8;
  const unsigned short* wu_src = Wu + (size_t)e * FF * DIM
                               + (size_t)(nt * 128 + (t >> 2)) * DIM + (t & 3) * 8;
  char* BgB = (char*)Bg + wid * 1024;
  char* BuB = (char*)Bu + wid * 1024;

  f32x4 accg[4][4] = {};
  f32x4 accu[4][4] = {};
  int fr = lane & 15, fk = (lane >> 4) * 8;

  for (int k0 = 0; k0 < DIM; k0 += 32) {
    __builtin_amdgcn_global_load_lds(GPTR(wg_src + k0),            LPTR(BgB),        16, 0, 0);
    __builtin_amdgcn_global_load_lds(GPTR(wg_src + k0 + 64 * DIM), LPTR(BgB + 4096), 16, 0, 0);
    __builtin_amdgcn_global_load_lds(GPTR(wu_src + k0),            LPTR(BuB),        16, 0, 0);
    __builtin_amdgcn_global_load_lds(GPTR(wu_src + k0 + 64 * DIM), LPTR(BuB + 4096), 16, 0, 0);

    float4 a0 = *(const float4*)(xsrc + k0);
    float4 a1 = *(const float4*)(xsrc + k0 + 4);
    float4 a2 = *(const float4*)(xsrc + k0 + 8);
    float4 a3 = *(const float4*)(xsrc + k0 + 12);
    *(bf16x8*)&As[row_a * 32 + kseg]     = pack8(a0, a1);
    *(bf16x8*)&As[row_a * 32 + kseg + 8] = pack8(a2, a3);

    __syncthreads();

    bf16x8 af[4], bg[4], bu[4];
    #pragma unroll
    for (int mf = 0; mf < 4; ++mf)
      af[mf] = *(bf16x8*)&As[(wm * 64 + mf * 16 + fr) * 32 + fk];
    #pragma unroll
    for (int nf = 0; nf < 4; ++nf) {
      bg[nf] = *(bf16x8*)&Bg[(wn * 64 + nf * 16 + fr) * 32 + fk];
      bu[nf] = *(bf16x8*)&Bu[(wn * 64 + nf * 16 + fr) * 32 + fk];
    }
    #pragma unroll
    for (int mf = 0; mf < 4; ++mf) {
      #pragma unroll
      for (int nf = 0; nf < 4; ++nf) {
        accg[mf][nf] = __builtin_amdgcn_mfma_f32_16x16x32_bf16(af[mf], bg[nf], accg[mf][nf], 0, 0, 0);
        accu[mf][nf] = __builtin_amdgcn_mfma_f32_16x16x32_bf16(af[mf], bu[nf], accu[mf][nf], 0, 0, 0);
      }
    }
    __syncthreads();
  }

  int fq = lane >> 4;
  #pragma unroll
  for (int mf = 0; mf < 4; ++mf) {
    #pragma unroll
    for (int v = 0; v < 4; ++v) {
      int rl = wm * 64 + mf * 16 + fq * 4 + v;
      if (rl < mrows) {
        size_t ro = (size_t)(base + mt * 128 + rl) * FF + nt * 128 + wn * 64 + fr;
        #pragma unroll
        for (int nf = 0; nf < 4; ++nf) {
          float g = accg[mf][nf][v];
          float u = accu[mf][nf][v];
          float h = g / (1.0f + __expf(-g)) * u;   // silu(g) * u
          Hb[ro + nf * 16] = f2bf(h);
        }
      }
    }
  }
}

// ---------------- GEMM2: Out[perm[row]] = H Wd^T, per expert
__global__ __launch_bounds__(256) void k_gemm2(
    const unsigned short* __restrict__ Hb,
    const unsigned short* __restrict__ Wd,
    const int* __restrict__ meta,
    const int* __restrict__ perm,
    float* __restrict__ Out)
{
  const int NT = DIM / 128;     // 16
  const int MT = NTOK / 128;    // 128
  int bx = blockIdx.x;
  int e  = bx / (MT * NT);
  int rr = bx % (MT * NT);
  int mt = rr / NT, nt = rr % NT;
  int cnt = meta[e];
  if (mt * 128 >= cnt) return;
  int base  = meta[8 + e];
  int mrows = cnt - mt * 128; if (mrows > 128) mrows = 128;

  __shared__ unsigned short As[128 * 32];
  __shared__ unsigned short Bs[128 * 32];

  int t = threadIdx.x;
  int lane = t & 63, wid = t >> 6;
  int wm = wid >> 1, wn = wid & 1;

  int r0 = mt * 128 + (t >> 2);
  int c0 = (t & 3) * 8;
  int ra = r0      < cnt ? r0      : cnt - 1;
  int rb = r0 + 64 < cnt ? r0 + 64 : cnt - 1;
  const unsigned short* ha  = Hb + (size_t)(base + ra) * FF + c0;
  const unsigned short* hb2 = Hb + (size_t)(base + rb) * FF + c0;
  const unsigned short* wd_src = Wd + (size_t)e * DIM * FF
                               + (size_t)(nt * 128 + (t >> 2)) * FF + c0;
  char* AsB = (char*)As + wid * 1024;
  char* BsB = (char*)Bs + wid * 1024;

  f32x4 acc[4][4] = {};
  int fr = lane & 15, fk = (lane >> 4) * 8;

  for (int k0 = 0; k0 < FF; k0 += 32) {
    __builtin_amdgcn_global_load_lds(GPTR(ha  + k0),           LPTR(AsB),        16, 0, 0);
    __builtin_amdgcn_global_load_lds(GPTR(hb2 + k0),           LPTR(AsB + 4096), 16, 0, 0);
    __builtin_amdgcn_global_load_lds(GPTR(wd_src + k0),          LPTR(BsB),        16, 0, 0);
    __builtin_amdgcn_global_load_lds(GPTR(wd_src + k0 + 64 * FF), LPTR(BsB + 4096), 16, 0, 0);

    __syncthreads();

    bf16x8 af[4], bf[4];
    #pragma unroll
    for (int mf = 0; mf < 4; ++mf)
      af[mf] = *(bf16x8*)&As[(wm * 64 + mf * 16 + fr) * 32 + fk];
    #pragma unroll
    for (int nf = 0; nf < 4; ++nf)
      bf[nf] = *(bf16x8*)&Bs[(wn * 64 + nf * 16 + fr) * 32 + fk];
    #pragma unroll
    for (int mf = 0; mf < 4; ++mf) {
      #pragma unroll
      for (int nf = 0; nf < 4; ++nf)
        acc[mf][nf] = __builtin_amdgcn_mfma_f32_16x16x32_bf16(af[mf], bf[nf], acc[mf][nf], 0, 0, 0);
    }
    __syncthreads();
  }

  int fq = lane >> 4;
  #pragma unroll
  for (int mf = 0; mf < 4; ++mf) {
    #pragma unroll
    for (int v = 0; v < 4; ++v) {
      int rl = wm * 64 + mf * 16 + fq * 4 + v;
      if (rl < mrows) {
        int tok = perm[base + mt * 128 + rl];
        float* o = Out + (size_t)tok * DIM + nt * 128 + wn * 64 + fr;
        #pragma unroll
        for (int nf = 0; nf < 4; ++nf)
          o[nf * 16] = acc[mf][nf][v];
      }
    }
  }
}

extern "C" void kernel_launch(void* const* d_in, const int* in_sizes, int n_in,
                              void* d_out, int out_size, void* d_ws, size_t ws_size,
                              hipStream_t stream) {
  (void)in_sizes; (void)n_in; (void)out_size; (void)ws_size;
  const float* X   = (const float*)d_in[0];
  const int*   tok = (const int*)d_in[1];
  const float* Wg  = (const float*)d_in[2];
  const float* Wu  = (const float*)d_in[3];
  const float* Wd  = (const float*)d_in[4];
  float* Out = (float*)d_out;

  char* ws = (char*)d_ws;
  int* meta = (int*)ws;                         // 12 ints
  int* eid  = (int*)(ws + 256);                 // 16384 ints
  int* perm = (int*)(ws + 256 + 4 * NTOK);      // 16384 ints
  unsigned short* Wbf  = (unsigned short*)(ws + 131328);
  unsigned short* WgBf = Wbf;
  unsigned short* WuBf = Wbf + (size_t)NE * FF * DIM;
  unsigned short* WdBf = Wbf + 2 * (size_t)NE * FF * DIM;
  unsigned short* Hb   = (unsigned short*)(ws + 131328 + 3ull * NE * FF * DIM * 2);
  // total ws use: 131328 + 100663296 + 67108864 = 167,903,488 bytes (~160 MiB)

  k_init   <<<1, 64, 0, stream>>>(meta);
  k_assign <<<NTOK / 256, 256, 0, stream>>>(tok, eid, meta);
  k_prefix <<<1, 64, 0, stream>>>(meta);
  k_scatter<<<NTOK / 256, 256, 0, stream>>>(eid, meta, perm);
  k_cast   <<<dim3((unsigned)((size_t)NE * FF * DIM / 2048), 3), 256, 0, stream>>>(Wg, Wu, Wd, Wbf);
  k_gemm1  <<<NE * (NTOK / 128) * (FF / 128), 256, 0, stream>>>(X, WgBf, WuBf, meta, perm, Hb);
  k_gemm2  <<<NE * (NTOK / 128) * (DIM / 128), 256, 0, stream>>>(Hb, WdBf, meta, perm, Out);
}

// Round 2
// 1069.247 us; speedup vs baseline: 1.4078x; 1.4078x over previous
//
#include <hip/hip_runtime.h>
#include <hip/hip_bf16.h>

#define NE      4
#define DIM     2048      // model dim: K of gemm1, N of gemm2
#define FF      2048      // per-expert hidden: N of gemm1, K of gemm2
#define NTOK    16384
#define VOCABSZ 100000
#define TPE     (VOCABSZ / NE)
#define SLICE   ((size_t)NE * FF * DIM)   // 16,777,216 elems = 32 MiB bf16

typedef __attribute__((ext_vector_type(8))) short bf16x8;
typedef __attribute__((ext_vector_type(4))) float f32x4;

#define GPTR(p) ((const __attribute__((address_space(1))) void*)(p))
#define LPTR(p) ((__attribute__((address_space(3))) void*)(p))
#define MFMA    __builtin_amdgcn_mfma_f32_16x16x32_bf16

__device__ __forceinline__ unsigned short f2bf(float f) {
  unsigned u = __builtin_bit_cast(unsigned, f);
  u += 0x7fffu + ((u >> 16) & 1u);          // RNE
  return (unsigned short)(u >> 16);
}

__device__ __forceinline__ bf16x8 pack8(float4 a, float4 b) {
  bf16x8 r;
  r[0] = (short)f2bf(a.x); r[1] = (short)f2bf(a.y);
  r[2] = (short)f2bf(a.z); r[3] = (short)f2bf(a.w);
  r[4] = (short)f2bf(b.x); r[5] = (short)f2bf(b.y);
  r[6] = (short)f2bf(b.z); r[7] = (short)f2bf(b.w);
  return r;
}

// meta: [0..3]=counts [4..7]=cursors [8..11]=offsets [12]=ntiles
__global__ void k_init(int* meta) { if (threadIdx.x < 16) meta[threadIdx.x] = 0; }

__global__ void k_assign(const int* __restrict__ tok, int* __restrict__ eid,
                         int* __restrict__ meta) {
  int i = blockIdx.x * 256 + threadIdx.x;
  int t = tok[i];
  t = t < 0 ? 0 : (t >= VOCABSZ ? VOCABSZ - 1 : t);
  int e = t / TPE; if (e > NE - 1) e = NE - 1;
  eid[i] = e;
  atomicAdd(&meta[e], 1);
}

__global__ void k_prefix(int* meta, int* tlist) {
  if (threadIdx.x == 0 && blockIdx.x == 0) {
    int s = 0, n = 0;
    for (int e = 0; e < NE; ++e) {
      meta[8 + e] = s;
      int c = meta[e]; s += c;
      for (int m = 0; m * 128 < c; ++m) tlist[n++] = (e << 16) | m;
    }
    meta[12] = n;
  }
}

__global__ void k_scatter(const int* __restrict__ eid, int* __restrict__ meta,
                          int* __restrict__ perm) {
  int i = blockIdx.x * 256 + threadIdx.x;
  int e = eid[i];
  int pos = meta[8 + e] + atomicAdd(&meta[4 + e], 1);
  perm[pos] = i;
}

// cast Wg, Wu, Wd, X (5 x SLICE fp32) -> contiguous bf16
__global__ void k_cast5(const float* __restrict__ wg, const float* __restrict__ wu,
                        const float* __restrict__ wd, const float* __restrict__ x,
                        unsigned short* __restrict__ dst) {
  int y = blockIdx.y;
  const float* s;
  if (y == 0) s = wg; else if (y == 1) s = wu; else if (y == 2) s = wd;
  else if (y == 3) s = x; else s = x + SLICE;
  unsigned short* d = dst + (size_t)y * SLICE;
  size_t i = ((size_t)blockIdx.x * 256 + threadIdx.x) * 8;
  float4 a = *(const float4*)(s + i);
  float4 b = *(const float4*)(s + i + 4);
  *(bf16x8*)(d + i) = pack8(a, b);
}

// ---------------- GEMM1: Hb = silu(X Wg^T) * (X Wu^T), rows grouped by expert
// 128x128 tile, BK=64, swizzled LDS (slot ^= row&7), all staging via global_load_lds
__global__ __launch_bounds__(256) void k_gemm1(
    const unsigned short* __restrict__ Xb,
    const unsigned short* __restrict__ Wgb,
    const unsigned short* __restrict__ Wub,
    const int* __restrict__ meta,
    const int* __restrict__ perm,
    const int* __restrict__ tlist,
    unsigned short* __restrict__ Hb)
{
  int ti = blockIdx.y;
  if (ti >= meta[12]) return;
  int pk = tlist[ti];
  int e = pk >> 16, mt = pk & 0xffff;
  int nt = blockIdx.x;
  int cnt = meta[e], base = meta[8 + e];
  int mrows = cnt - mt * 128; if (mrows > 128) mrows = 128;

  __shared__ unsigned short As[128 * 64];
  __shared__ unsigned short Bg[128 * 64];
  __shared__ unsigned short Bu[128 * 64];

  int t = threadIdx.x, lane = t & 63, wid = t >> 6;
  int wm = wid >> 1, wn = wid & 1;

  // staging geometry: load l covers rows [l*32, l*32+32); thread t -> row l*32 + (t>>3),
  // LDS slot (t&7); source fetches swizzled slot (t&7)^(row&7)
  int rsub = t >> 3;                      // 0..31
  int sl   = (t & 7) ^ (rsub & 7);        // pre-swizzled source slot
  const unsigned short* asrc[4];
  const unsigned short* gsrc[4];
  const unsigned short* usrc[4];
  #pragma unroll
  for (int l = 0; l < 4; ++l) {
    int r = l * 32 + rsub;
    int gr = mt * 128 + r; if (gr >= cnt) gr = cnt - 1;   // clamp (dup rows, guarded store)
    asrc[l] = Xb + (size_t)perm[base + gr] * DIM + sl * 8;
    size_t wrow = (size_t)e * FF * DIM + (size_t)(nt * 128 + r) * DIM + sl * 8;
    gsrc[l] = Wgb + wrow;
    usrc[l] = Wub + wrow;
  }
  char* aB = (char*)As + wid * 1024;
  char* gB = (char*)Bg + wid * 1024;
  char* uB = (char*)Bu + wid * 1024;

  f32x4 accg[4][4] = {};
  f32x4 accu[4][4] = {};
  int fr = lane & 15, fc = lane >> 4, sx = fr & 7;
  int aoff[4], boff[4];
  #pragma unroll
  for (int i = 0; i < 4; ++i) {
    aoff[i] = (wm * 64 + i * 16 + fr) * 128;
    boff[i] = (wn * 64 + i * 16 + fr) * 128;
  }
  const char* asb = (const char*)As;
  const char* gsb = (const char*)Bg;
  const char* usb = (const char*)Bu;

  for (int k0 = 0; k0 < DIM; k0 += 64) {
    #pragma unroll
    for (int l = 0; l < 4; ++l) {
      __builtin_amdgcn_global_load_lds(GPTR(asrc[l] + k0), LPTR(aB + l * 4096), 16, 0, 0);
      __builtin_amdgcn_global_load_lds(GPTR(gsrc[l] + k0), LPTR(gB + l * 4096), 16, 0, 0);
      __builtin_amdgcn_global_load_lds(GPTR(usrc[l] + k0), LPTR(uB + l * 4096), 16, 0, 0);
    }
    __syncthreads();
    #pragma unroll
    for (int kk = 0; kk < 2; ++kk) {
      int so = ((kk * 4 + fc) ^ sx) * 16;
      bf16x8 af[4];
      #pragma unroll
      for (int mf = 0; mf < 4; ++mf)
        af[mf] = *(const bf16x8*)(asb + aoff[mf] + so);
      #pragma unroll
      for (int nf = 0; nf < 4; ++nf) {
        bf16x8 bg = *(const bf16x8*)(gsb + boff[nf] + so);
        bf16x8 bu = *(const bf16x8*)(usb + boff[nf] + so);
        #pragma unroll
        for (int mf = 0; mf < 4; ++mf) {
          accg[mf][nf] = MFMA(af[mf], bg, accg[mf][nf], 0, 0, 0);
          accu[mf][nf] = MFMA(af[mf], bu, accu[mf][nf], 0, 0, 0);
        }
      }
    }
    __syncthreads();
  }

  int fq = lane >> 4;
  #pragma unroll
  for (int mf = 0; mf < 4; ++mf) {
    #pragma unroll
    for (int v = 0; v < 4; ++v) {
      int rl = wm * 64 + mf * 16 + fq * 4 + v;
      if (rl < mrows) {
        size_t ro = (size_t)(base + mt * 128 + rl) * FF + nt * 128 + wn * 64 + fr;
        #pragma unroll
        for (int nf = 0; nf < 4; ++nf) {
          float g = accg[mf][nf][v];
          float u = accu[mf][nf][v];
          float h = g / (1.0f + __expf(-g)) * u;
          Hb[ro + nf * 16] = f2bf(h);
        }
      }
    }
  }
}

// ---------------- GEMM2: Out[perm[row]] = Hb Wd^T
__global__ __launch_bounds__(256) void k_gemm2(
    const unsigned short* __restrict__ Hb,
    const unsigned short* __restrict__ Wdb,
    const int* __restrict__ meta,
    const int* __restrict__ perm,
    const int* __restrict__ tlist,
    float* __restrict__ Out)
{
  int ti = blockIdx.y;
  if (ti >= meta[12]) return;
  int pk = tlist[ti];
  int e = pk >> 16, mt = pk & 0xffff;
  int nt = blockIdx.x;
  int cnt = meta[e], base = meta[8 + e];
  int mrows = cnt - mt * 128; if (mrows > 128) mrows = 128;

  __shared__ unsigned short As[128 * 64];
  __shared__ unsigned short Bs[128 * 64];

  int t = threadIdx.x, lane = t & 63, wid = t >> 6;
  int wm = wid >> 1, wn = wid & 1;

  int rsub = t >> 3;
  int sl   = (t & 7) ^ (rsub & 7);
  const unsigned short* asrc[4];
  const unsigned short* bsrc[4];
  #pragma unroll
  for (int l = 0; l < 4; ++l) {
    int r = l * 32 + rsub;
    int gr = mt * 128 + r; if (gr >= cnt) gr = cnt - 1;
    asrc[l] = Hb + (size_t)(base + gr) * FF + sl * 8;
    bsrc[l] = Wdb + (size_t)e * DIM * FF + (size_t)(nt * 128 + r) * FF + sl * 8;
  }
  char* aB = (char*)As + wid * 1024;
  char* bB = (char*)Bs + wid * 1024;

  f32x4 acc[4][4] = {};
  int fr = lane & 15, fc = lane >> 4, sx = fr & 7;
  int aoff[4], boff[4];
  #pragma unroll
  for (int i = 0; i < 4; ++i) {
    aoff[i] = (wm * 64 + i * 16 + fr) * 128;
    boff[i] = (wn * 64 + i * 16 + fr) * 128;
  }
  const char* asb = (const char*)As;
  const char* bsb = (const char*)Bs;

  for (int k0 = 0; k0 < FF; k0 += 64) {
    #pragma unroll
    for (int l = 0; l < 4; ++l) {
      __builtin_amdgcn_global_load_lds(GPTR(asrc[l] + k0), LPTR(aB + l * 4096), 16, 0, 0);
      __builtin_amdgcn_global_load_lds(GPTR(bsrc[l] + k0), LPTR(bB + l * 4096), 16, 0, 0);
    }
    __syncthreads();
    #pragma unroll
    for (int kk = 0; kk < 2; ++kk) {
      int so = ((kk * 4 + fc) ^ sx) * 16;
      bf16x8 af[4], bf[4];
      #pragma unroll
      for (int mf = 0; mf < 4; ++mf)
        af[mf] = *(const bf16x8*)(asb + aoff[mf] + so);
      #pragma unroll
      for (int nf = 0; nf < 4; ++nf)
        bf[nf] = *(const bf16x8*)(bsb + boff[nf] + so);
      #pragma unroll
      for (int mf = 0; mf < 4; ++mf) {
        #pragma unroll
        for (int nf = 0; nf < 4; ++nf)
          acc[mf][nf] = MFMA(af[mf], bf[nf], acc[mf][nf], 0, 0, 0);
      }
    }
    __syncthreads();
  }

  int fq = lane >> 4;
  #pragma unroll
  for (int mf = 0; mf < 4; ++mf) {
    #pragma unroll
    for (int v = 0; v < 4; ++v) {
      int rl = wm * 64 + mf * 16 + fq * 4 + v;
      if (rl < mrows) {
        int tok = perm[base + mt * 128 + rl];
        float* o = Out + (size_t)tok * DIM + nt * 128 + wn * 64 + fr;
        #pragma unroll
        for (int nf = 0; nf < 4; ++nf)
          o[nf * 16] = acc[mf][nf][v];
      }
    }
  }
}

extern "C" void kernel_launch(void* const* d_in, const int* in_sizes, int n_in,
                              void* d_out, int out_size, void* d_ws, size_t ws_size,
                              hipStream_t stream) {
  (void)in_sizes; (void)n_in; (void)out_size; (void)ws_size;
  const float* X   = (const float*)d_in[0];
  const int*   tok = (const int*)d_in[1];
  const float* Wg  = (const float*)d_in[2];
  const float* Wu  = (const float*)d_in[3];
  const float* Wd  = (const float*)d_in[4];
  float* Out = (float*)d_out;

  char* ws = (char*)d_ws;
  int* meta  = (int*)ws;                      // 16 ints
  int* tlist = (int*)(ws + 64);               // up to 256 tiles
  int* eid   = (int*)(ws + 2048);             // 16384 ints
  int* perm  = (int*)(ws + 2048 + 65536);     // 16384 ints
  unsigned short* Wbf  = (unsigned short*)(ws + 133120);
  unsigned short* WgBf = Wbf;
  unsigned short* WuBf = Wbf + SLICE;
  unsigned short* WdBf = Wbf + 2 * SLICE;
  unsigned short* Xbf  = Wbf + 3 * SLICE;     // 2 slices (NTOK*DIM)
  unsigned short* Hb   = Wbf + 5 * SLICE;     // NTOK*FF
  // total ws use: 133120 + 5*33554432 + 67108864 = 235,014,144 bytes (~224 MiB)

  k_init   <<<1, 64, 0, stream>>>(meta);
  k_assign <<<NTOK / 256, 256, 0, stream>>>(tok, eid, meta);
  k_prefix <<<1, 64, 0, stream>>>(meta, tlist);
  k_scatter<<<NTOK / 256, 256, 0, stream>>>(eid, meta, perm);
  k_cast5  <<<dim3((unsigned)(SLICE / 2048), 5), 256, 0, stream>>>(Wg, Wu, Wd, X, Wbf);
  k_gemm1  <<<dim3(FF / 128, 132), 256, 0, stream>>>(Xbf, WgBf, WuBf, meta, perm, tlist, Hb);
  k_gemm2  <<<dim3(DIM / 128, 132), 256, 0, stream>>>(Hb, WdBf, meta, perm, tlist, Out);
}

// Round 3
// 764.064 us; speedup vs baseline: 1.9701x; 1.3994x over previous
//
#include <hip/hip_runtime.h>
#include <hip/hip_bf16.h>

#define NE      4
#define DIM     2048      // model dim: K of gemm1, N of gemm2
#define FF      2048      // per-expert hidden: N of gemm1, K of gemm2
#define NTOK    16384
#define VOCABSZ 100000
#define TPE     (VOCABSZ / NE)
#define SLICE   ((size_t)NE * FF * DIM)   // 16,777,216 elems = 32 MiB bf16
#define NYT     68                        // max 256-row tiles over all experts

typedef __attribute__((ext_vector_type(8))) short bf16x8;
typedef __attribute__((ext_vector_type(4))) float f32x4;

#define GPTR(p) ((const __attribute__((address_space(1))) void*)(p))
#define LPTR(p) ((__attribute__((address_space(3))) void*)(p))
#define MFMA    __builtin_amdgcn_mfma_f32_16x16x32_bf16
#define GLL(g, l) __builtin_amdgcn_global_load_lds(GPTR(g), LPTR(l), 16, 0, 0)

__device__ __forceinline__ unsigned short f2bf(float f) {
  unsigned u = __builtin_bit_cast(unsigned, f);
  u += 0x7fffu + ((u >> 16) & 1u);          // RNE
  return (unsigned short)(u >> 16);
}

__device__ __forceinline__ bf16x8 pack8(float4 a, float4 b) {
  bf16x8 r;
  r[0] = (short)f2bf(a.x); r[1] = (short)f2bf(a.y);
  r[2] = (short)f2bf(a.z); r[3] = (short)f2bf(a.w);
  r[4] = (short)f2bf(b.x); r[5] = (short)f2bf(b.y);
  r[6] = (short)f2bf(b.z); r[7] = (short)f2bf(b.w);
  return r;
}

// meta: [0..3]=counts [4..7]=cursors [8..11]=offsets [12]=ntiles(256)
__global__ void k_init(int* meta) { if (threadIdx.x < 16) meta[threadIdx.x] = 0; }

__global__ void k_assign(const int* __restrict__ tok, int* __restrict__ eid,
                         int* __restrict__ meta) {
  int i = blockIdx.x * 256 + threadIdx.x;
  int t = tok[i];
  t = t < 0 ? 0 : (t >= VOCABSZ ? VOCABSZ - 1 : t);
  int e = t / TPE; if (e > NE - 1) e = NE - 1;
  eid[i] = e;
  atomicAdd(&meta[e], 1);
}

__global__ void k_prefix(int* meta, int* tlist) {
  if (threadIdx.x == 0 && blockIdx.x == 0) {
    int s = 0, n = 0;
    for (int e = 0; e < NE; ++e) {
      meta[8 + e] = s;
      int c = meta[e]; s += c;
      for (int m = 0; m * 256 < c; ++m) tlist[n++] = (e << 16) | m;
    }
    meta[12] = n;
  }
}

__global__ void k_scatter(const int* __restrict__ eid, int* __restrict__ meta,
                          int* __restrict__ perm) {
  int i = blockIdx.x * 256 + threadIdx.x;
  int e = eid[i];
  int pos = meta[8 + e] + atomicAdd(&meta[4 + e], 1);
  perm[pos] = i;
}

// cast Wg, Wu, Wd, X (5 x SLICE fp32) -> contiguous bf16
__global__ void k_cast5(const float* __restrict__ wg, const float* __restrict__ wu,
                        const float* __restrict__ wd, const float* __restrict__ x,
                        unsigned short* __restrict__ dst) {
  int y = blockIdx.y;
  const float* s;
  if (y == 0) s = wg; else if (y == 1) s = wu; else if (y == 2) s = wd;
  else if (y == 3) s = x; else s = x + SLICE;
  unsigned short* d = dst + (size_t)y * SLICE;
  size_t i = ((size_t)blockIdx.x * 256 + threadIdx.x) * 8;
  float4 a = *(const float4*)(s + i);
  float4 b = *(const float4*)(s + i + 4);
  *(bf16x8*)(d + i) = pack8(a, b);
}

// ---------------- GEMM1: Hb = silu(X Wg^T) * (X Wu^T)
// BM=256, dual-B 128(g)+128(u), BK=64, 8 waves (2M x 4N), 2-deep counted-vmcnt pipeline
__global__ __launch_bounds__(512, 2) void k_gemm1(
    const unsigned short* __restrict__ Xb,
    const unsigned short* __restrict__ Wgb,
    const unsigned short* __restrict__ Wub,
    const int* __restrict__ meta,
    const int* __restrict__ perm,
    const int* __restrict__ tlist,
    unsigned short* __restrict__ Hb)
{
  // XCD-aware remap: contiguous x-major chunks per XCD (NWG = 16*NYT, %8==0)
  int L = blockIdx.y * gridDim.x + blockIdx.x;
  int NWG = gridDim.x * gridDim.y;
  int logical = (L & 7) * (NWG >> 3) + (L >> 3);
  int nt = logical / NYT;           // 0..15 (N tile: 128 g-cols + 128 u-cols)
  int ti = logical % NYT;
  if (ti >= meta[12]) return;
  int pk = tlist[ti];
  int e = pk >> 16, mt = pk & 0xffff;
  int cnt = meta[e], base = meta[8 + e];
  int mrows = cnt - mt * 256; if (mrows > 256) mrows = 256;

  // LDS: per buffer 64KB: A[256][64] @0, Bg[128][64] @32768, Bu[128][64] @49152
  __shared__ __align__(16) char smem[131072];

  int t = threadIdx.x, lane = t & 63, wid = t >> 6;
  int wm = wid >> 2, wn = wid & 3;

  // ---- staging addresses (pre-swizzled global source, linear LDS dest)
  int rsub = t >> 3;                          // 0..63 row within each 64-row chunk
  int swb = ((t & 7) ^ (rsub & 7)) * 8;       // swizzled 16B-slot (elem offset)
  const unsigned short* asrc[4];
  #pragma unroll
  for (int l = 0; l < 4; ++l) {
    int gr = mt * 256 + l * 64 + rsub; if (gr >= cnt) gr = cnt - 1;
    asrc[l] = Xb + (size_t)perm[base + gr] * DIM + swb;
  }
  const unsigned short* gsrc[2];
  const unsigned short* usrc[2];
  #pragma unroll
  for (int l = 0; l < 2; ++l) {
    size_t wrow = (size_t)e * FF * DIM + (size_t)(nt * 128 + l * 64 + rsub) * DIM + swb;
    gsrc[l] = Wgb + wrow;
    usrc[l] = Wub + wrow;
  }

  // ---- fragment read offsets
  int fr = lane & 15, fc = lane >> 4, sx = fr & 7, fq = lane >> 4;
  int aoff[8], goff[2];
  #pragma unroll
  for (int m = 0; m < 8; ++m) aoff[m] = (wm * 128 + m * 16 + fr) * 128;
  #pragma unroll
  for (int n = 0; n < 2; ++n) goff[n] = (wn * 32 + n * 16 + fr) * 128;

  f32x4 accg[8][2] = {};
  f32x4 accu[8][2] = {};

  auto stage = [&](int b, int k0) {
    char* bb = smem + b * 65536 + wid * 1024;
    GLL(asrc[0] + k0, bb);
    GLL(asrc[1] + k0, bb + 8192);
    GLL(asrc[2] + k0, bb + 16384);
    GLL(asrc[3] + k0, bb + 24576);
    GLL(gsrc[0] + k0, bb + 32768);
    GLL(gsrc[1] + k0, bb + 40960);
    GLL(usrc[0] + k0, bb + 49152);
    GLL(usrc[1] + k0, bb + 57344);
  };

  auto compute = [&](int b) {
    const char* Ab = smem + b * 65536;
    const char* Gb = Ab + 32768;
    const char* Ub = Ab + 49152;
    #pragma unroll
    for (int kk = 0; kk < 2; ++kk) {
      int so = ((kk * 4 + fc) ^ sx) * 16;
      bf16x8 af[8];
      #pragma unroll
      for (int m = 0; m < 8; ++m) af[m] = *(const bf16x8*)(Ab + aoff[m] + so);
      bf16x8 g0 = *(const bf16x8*)(Gb + goff[0] + so);
      bf16x8 g1 = *(const bf16x8*)(Gb + goff[1] + so);
      bf16x8 u0 = *(const bf16x8*)(Ub + goff[0] + so);
      bf16x8 u1 = *(const bf16x8*)(Ub + goff[1] + so);
      #pragma unroll
      for (int m = 0; m < 8; ++m) {
        accg[m][0] = MFMA(af[m], g0, accg[m][0], 0, 0, 0);
        accg[m][1] = MFMA(af[m], g1, accg[m][1], 0, 0, 0);
        accu[m][0] = MFMA(af[m], u0, accu[m][0], 0, 0, 0);
        accu[m][1] = MFMA(af[m], u1, accu[m][1], 0, 0, 0);
      }
    }
  };

  const int NTILES = DIM / 64;    // 32
  stage(0, 0);
  stage(1, 64);
  for (int kt = 0; kt < NTILES - 1; ++kt) {
    int b = kt & 1;
    asm volatile("s_waitcnt vmcnt(8)" ::: "memory");
    __builtin_amdgcn_s_barrier();
    compute(b);
    __builtin_amdgcn_s_barrier();
    if (kt + 2 < NTILES) stage(b, (kt + 2) * 64);
  }
  asm volatile("s_waitcnt vmcnt(0)" ::: "memory");
  __builtin_amdgcn_s_barrier();
  compute(1);

  #pragma unroll
  for (int m = 0; m < 8; ++m) {
    #pragma unroll
    for (int v = 0; v < 4; ++v) {
      int rl = wm * 128 + m * 16 + fq * 4 + v;
      if (rl < mrows) {
        size_t ro = (size_t)(base + mt * 256 + rl) * FF + nt * 128 + wn * 32 + fr;
        float g0 = accg[m][0][v], u0 = accu[m][0][v];
        float g1 = accg[m][1][v], u1 = accu[m][1][v];
        Hb[ro]      = f2bf(g0 / (1.0f + __expf(-g0)) * u0);
        Hb[ro + 16] = f2bf(g1 / (1.0f + __expf(-g1)) * u1);
      }
    }
  }
}

// ---------------- GEMM2: Out[perm[row]] = Hb Wd^T   (BM=BN=256, BK=64)
__global__ __launch_bounds__(512, 2) void k_gemm2(
    const unsigned short* __restrict__ Hb,
    const unsigned short* __restrict__ Wdb,
    const int* __restrict__ meta,
    const int* __restrict__ perm,
    const int* __restrict__ tlist,
    float* __restrict__ Out)
{
  int L = blockIdx.y * gridDim.x + blockIdx.x;
  int NWG = gridDim.x * gridDim.y;
  int logical = (L & 7) * (NWG >> 3) + (L >> 3);
  int nt = logical / NYT;           // 0..7 (256 output cols each)
  int ti = logical % NYT;
  if (ti >= meta[12]) return;
  int pk = tlist[ti];
  int e = pk >> 16, mt = pk & 0xffff;
  int cnt = meta[e], base = meta[8 + e];
  int mrows = cnt - mt * 256; if (mrows > 256) mrows = 256;

  // LDS: per buffer 64KB: A[256][64] @0, B[256][64] @32768
  __shared__ __align__(16) char smem[131072];

  int t = threadIdx.x, lane = t & 63, wid = t >> 6;
  int wm = wid >> 2, wn = wid & 3;

  int rsub = t >> 3;
  int swb = ((t & 7) ^ (rsub & 7)) * 8;
  const unsigned short* asrc[4];
  const unsigned short* bsrc[4];
  #pragma unroll
  for (int l = 0; l < 4; ++l) {
    int gr = mt * 256 + l * 64 + rsub; if (gr >= cnt) gr = cnt - 1;
    asrc[l] = Hb + (size_t)(base + gr) * FF + swb;
    bsrc[l] = Wdb + (size_t)e * DIM * FF + (size_t)(nt * 256 + l * 64 + rsub) * FF + swb;
  }

  int fr = lane & 15, fc = lane >> 4, sx = fr & 7, fq = lane >> 4;
  int aoff[8], boff[4];
  #pragma unroll
  for (int m = 0; m < 8; ++m) aoff[m] = (wm * 128 + m * 16 + fr) * 128;
  #pragma unroll
  for (int n = 0; n < 4; ++n) boff[n] = (wn * 64 + n * 16 + fr) * 128;

  f32x4 acc[8][4] = {};

  auto stage = [&](int b, int k0) {
    char* bb = smem + b * 65536 + wid * 1024;
    GLL(asrc[0] + k0, bb);
    GLL(asrc[1] + k0, bb + 8192);
    GLL(asrc[2] + k0, bb + 16384);
    GLL(asrc[3] + k0, bb + 24576);
    GLL(bsrc[0] + k0, bb + 32768);
    GLL(bsrc[1] + k0, bb + 40960);
    GLL(bsrc[2] + k0, bb + 49152);
    GLL(bsrc[3] + k0, bb + 57344);
  };

  auto compute = [&](int b) {
    const char* Ab = smem + b * 65536;
    const char* Bb = Ab + 32768;
    #pragma unroll
    for (int kk = 0; kk < 2; ++kk) {
      int so = ((kk * 4 + fc) ^ sx) * 16;
      bf16x8 af[8], bf[4];
      #pragma unroll
      for (int m = 0; m < 8; ++m) af[m] = *(const bf16x8*)(Ab + aoff[m] + so);
      #pragma unroll
      for (int n = 0; n < 4; ++n) bf[n] = *(const bf16x8*)(Bb + boff[n] + so);
      #pragma unroll
      for (int m = 0; m < 8; ++m) {
        #pragma unroll
        for (int n = 0; n < 4; ++n)
          acc[m][n] = MFMA(af[m], bf[n], acc[m][n], 0, 0, 0);
      }
    }
  };

  const int NTILES = FF / 64;     // 32
  stage(0, 0);
  stage(1, 64);
  for (int kt = 0; kt < NTILES - 1; ++kt) {
    int b = kt & 1;
    asm volatile("s_waitcnt vmcnt(8)" ::: "memory");
    __builtin_amdgcn_s_barrier();
    compute(b);
    __builtin_amdgcn_s_barrier();
    if (kt + 2 < NTILES) stage(b, (kt + 2) * 64);
  }
  asm volatile("s_waitcnt vmcnt(0)" ::: "memory");
  __builtin_amdgcn_s_barrier();
  compute(1);

  #pragma unroll
  for (int m = 0; m < 8; ++m) {
    #pragma unroll
    for (int v = 0; v < 4; ++v) {
      int rl = wm * 128 + m * 16 + fq * 4 + v;
      if (rl < mrows) {
        int tok = perm[base + mt * 256 + rl];
        float* o = Out + (size_t)tok * DIM + nt * 256 + wn * 64 + fr;
        #pragma unroll
        for (int n = 0; n < 4; ++n)
          o[n * 16] = acc[m][n][v];
      }
    }
  }
}

extern "C" void kernel_launch(void* const* d_in, const int* in_sizes, int n_in,
                              void* d_out, int out_size, void* d_ws, size_t ws_size,
                              hipStream_t stream) {
  (void)in_sizes; (void)n_in; (void)out_size; (void)ws_size;
  const float* X   = (const float*)d_in[0];
  const int*   tok = (const int*)d_in[1];
  const float* Wg  = (const float*)d_in[2];
  const float* Wu  = (const float*)d_in[3];
  const float* Wd  = (const float*)d_in[4];
  float* Out = (float*)d_out;

  char* ws = (char*)d_ws;
  int* meta  = (int*)ws;                      // 16 ints
  int* tlist = (int*)(ws + 64);               // up to ~68 tiles
  int* eid   = (int*)(ws + 2048);             // 16384 ints
  int* perm  = (int*)(ws + 2048 + 65536);     // 16384 ints
  unsigned short* Wbf  = (unsigned short*)(ws + 133120);
  unsigned short* WgBf = Wbf;
  unsigned short* WuBf = Wbf + SLICE;
  unsigned short* WdBf = Wbf + 2 * SLICE;
  unsigned short* Xbf  = Wbf + 3 * SLICE;     // 2 slices (NTOK*DIM)
  unsigned short* Hb   = Wbf + 5 * SLICE;     // NTOK*FF
  // total ws use: 133120 + 5*33554432 + 67108864 = 235,014,144 bytes (~224 MiB)

  k_init   <<<1, 64, 0, stream>>>(meta);
  k_assign <<<NTOK / 256, 256, 0, stream>>>(tok, eid, meta);
  k_prefix <<<1, 64, 0, stream>>>(meta, tlist);
  k_scatter<<<NTOK / 256, 256, 0, stream>>>(eid, meta, perm);
  k_cast5  <<<dim3((unsigned)(SLICE / 2048), 5), 256, 0, stream>>>(Wg, Wu, Wd, X, Wbf);
  k_gemm1  <<<dim3(FF / 128, NYT), 512, 0, stream>>>(Xbf, WgBf, WuBf, meta, perm, tlist, Hb);
  k_gemm2  <<<dim3(DIM / 256, NYT), 512, 0, stream>>>(Hb, WdBf, meta, perm, tlist, Out);
}